// Round 1
// baseline (7556.227 us; speedup 1.0000x reference)
//
#include <hip/hip_runtime.h>
#include <math.h>

#define T_ 4
#define B_ 8192
#define D_ 1024
#define U_ 512
#define E_ 8

// ============================================================================
// K1: level-0 gates.
// logits (per b): 104 cols. c<64: task t=c>>4, col j=c&15 from gw0 (T,D,16).
//                 c in [64,104): shared col j=c-64 from gws (D,40).
// softmax per (b,t) over 16 and per b over 40.
// out: g0 (T,B,16), gs (B,40)
// ============================================================================
__global__ __launch_bounds__(256) void gates0_kernel(
    const float* __restrict__ x, const float* __restrict__ gw0,
    const float* __restrict__ gb0, const float* __restrict__ gws,
    const float* __restrict__ gbs, float* __restrict__ g0,
    float* __restrict__ gs)
{
    __shared__ float xs[32 * 36];     // x tile [32 b][32 k], stride 36 (16B-aligned rows)
    __shared__ float wsh[32 * 104];   // w tile [32 k][104 c]; reused for logits [32 b][104 c]
    const int tid = threadIdx.x;
    const int bl = tid >> 3;          // 0..31
    const int lane = tid & 7;         // 0..7 (13 cols each)
    const int b0 = blockIdx.x * 32;

    float acc[13];
#pragma unroll
    for (int i = 0; i < 13; ++i) acc[i] = 0.f;

    for (int k0 = 0; k0 < D_; k0 += 32) {
        __syncthreads();
        {   // stage x: 32 rows x 32 k = 256 float4, 1 per thread
            const int r = tid >> 3, f = tid & 7;
            const float4 v = *reinterpret_cast<const float4*>(&x[(b0 + r) * D_ + k0 + f * 4]);
            *reinterpret_cast<float4*>(&xs[r * 36 + f * 4]) = v;
        }
        // stage w: 32 x 104 scalar
        for (int i = tid; i < 32 * 104; i += 256) {
            const int kk = i / 104, c = i - kk * 104;
            float v;
            if (c < 64) v = gw0[(c >> 4) * (D_ * 16) + (k0 + kk) * 16 + (c & 15)];
            else        v = gws[(k0 + kk) * 40 + (c - 64)];
            wsh[kk * 104 + c] = v;
        }
        __syncthreads();
#pragma unroll 8
        for (int kk = 0; kk < 32; ++kk) {
            const float a = xs[bl * 36 + kk];
#pragma unroll
            for (int c = 0; c < 13; ++c)
                acc[c] = fmaf(a, wsh[kk * 104 + lane * 13 + c], acc[c]);
        }
    }
    __syncthreads();
    // logits (+bias) into wsh as [32 b][104 c]
#pragma unroll
    for (int c = 0; c < 13; ++c) {
        const int col = lane * 13 + c;
        const float bias = (col < 64) ? gb0[col] : gbs[col - 64];
        wsh[bl * 104 + col] = acc[c] + bias;
    }
    __syncthreads();
    // softmax: 32 b x 5 groups
    if (tid < 160) {
        const int r = tid / 5, grp = tid - (tid / 5) * 5;
        const int base = r * 104 + (grp < 4 ? grp * 16 : 64);
        const int n = (grp < 4) ? 16 : 40;
        float m = -1e30f;
        for (int j = 0; j < n; ++j) m = fmaxf(m, wsh[base + j]);
        float s = 0.f;
        for (int j = 0; j < n; ++j) { const float e = expf(wsh[base + j] - m); wsh[base + j] = e; s += e; }
        const float inv = 1.f / s;
        const int b = b0 + r;
        if (grp < 4) { for (int j = 0; j < 16; ++j) g0[(grp * B_ + b) * 16 + j] = wsh[base + j] * inv; }
        else         { for (int j = 0; j < 40; ++j) gs[b * 40 + j] = wsh[base + j] * inv; }
    }
}

// ============================================================================
// K2: fused level-0. 5 GEMM planes (4 task ew0[t] + shared ews0), all K=1024,
// N=4096 row-major (n = u*8+e). Each thread owns (2 b) x (1 u) x (all 5 planes
// x 8 e) = 80 accumulators -> full relu+gate combine is thread-local.
// out: tout (5,B,U) = [task_out0 planes 0..3 | share_out plane 4]
// ============================================================================
__global__ __launch_bounds__(256) void fused0_kernel(
    const float* __restrict__ x, const float* __restrict__ ew0,
    const float* __restrict__ ews0, const float* __restrict__ eb0,
    const float* __restrict__ ebs0, const float* __restrict__ g0,
    const float* __restrict__ gs, float* __restrict__ tout)
{
    __shared__ float smem[2304 + 10240];   // 50 KB
    float* xs  = smem;          // [64 b][36]  (32 k used)
    float* wsh = smem + 2304;   // [5 p][32 k][64 n]

    const int tid = threadIdx.x;
    const int bp = tid >> 3;    // 0..31 (pair of b rows)
    const int ul = tid & 7;     // 0..7  (u within tile)
    const int b0 = blockIdx.x * 64;
    const int n0 = blockIdx.y * 64;
    const int u  = blockIdx.y * 8 + ul;

    float acc[2][5][8];
#pragma unroll
    for (int i = 0; i < 2; ++i)
#pragma unroll
        for (int p = 0; p < 5; ++p)
#pragma unroll
            for (int e = 0; e < 8; ++e) acc[i][p][e] = 0.f;

    for (int k0 = 0; k0 < D_; k0 += 32) {
        __syncthreads();
#pragma unroll
        for (int s = 0; s < 2; ++s) {        // x tile: 64x32 = 512 float4
            const int i = tid + s * 256;
            const int r = i >> 3, f = i & 7;
            const float4 v = *reinterpret_cast<const float4*>(&x[(b0 + r) * D_ + k0 + f * 4]);
            *reinterpret_cast<float4*>(&xs[r * 36 + f * 4]) = v;
        }
#pragma unroll
        for (int s = 0; s < 10; ++s) {       // w tiles: 5x32x64 = 2560 float4
            const int i = tid + s * 256;
            const int p = i >> 9;
            const int rem = i & 511;
            const int kk = rem >> 4, f = rem & 15;
            const float* Wp = (p < 4) ? (ew0 + p * (D_ * 4096)) : ews0;
            const float4 v = *reinterpret_cast<const float4*>(&Wp[(k0 + kk) * 4096 + n0 + f * 4]);
            *reinterpret_cast<float4*>(&wsh[p * 2048 + kk * 64 + f * 4]) = v;
        }
        __syncthreads();
#pragma unroll 4
        for (int kk = 0; kk < 32; ++kk) {
            const float a0 = xs[(bp * 2 + 0) * 36 + kk];
            const float a1 = xs[(bp * 2 + 1) * 36 + kk];
#pragma unroll
            for (int p = 0; p < 5; ++p) {
                const float4 w0 = *reinterpret_cast<const float4*>(&wsh[p * 2048 + kk * 64 + ul * 8]);
                const float4 w1 = *reinterpret_cast<const float4*>(&wsh[p * 2048 + kk * 64 + ul * 8 + 4]);
                const float w[8] = {w0.x, w0.y, w0.z, w0.w, w1.x, w1.y, w1.z, w1.w};
#pragma unroll
                for (int e = 0; e < 8; ++e) {
                    acc[0][p][e] = fmaf(a0, w[e], acc[0][p][e]);
                    acc[1][p][e] = fmaf(a1, w[e], acc[1][p][e]);
                }
            }
        }
    }
    // ---- epilogue: stage gates for the 64 b rows, combine, store ----
    __syncthreads();
    float* g0s = smem + 2304;          // [64 b][64]  (t*16+j)
    float* gss = smem + 2304 + 4096;   // [64 b][40]
    for (int i = tid; i < 64 * 64; i += 256) {
        const int r = i >> 6, c = i & 63;
        g0s[i] = g0[((c >> 4) * B_ + (b0 + r)) * 16 + (c & 15)];
    }
    for (int i = tid; i < 64 * 40; i += 256) {
        const int r = i / 40, c = i - r * 40;
        gss[i] = gs[(b0 + r) * 40 + c];
    }
    __syncthreads();

    float bias4[8];
    {
        const float4 v0 = *reinterpret_cast<const float4*>(&ebs0[u * 8]);
        const float4 v1 = *reinterpret_cast<const float4*>(&ebs0[u * 8 + 4]);
        bias4[0] = v0.x; bias4[1] = v0.y; bias4[2] = v0.z; bias4[3] = v0.w;
        bias4[4] = v1.x; bias4[5] = v1.y; bias4[6] = v1.z; bias4[7] = v1.w;
    }
#pragma unroll
    for (int bi = 0; bi < 2; ++bi) {
        const int bl = bp * 2 + bi;
        const int b = b0 + bl;
        float es_r[8];
#pragma unroll
        for (int e = 0; e < 8; ++e) es_r[e] = fmaxf(acc[bi][4][e] + bias4[e], 0.f);
        float sh = 0.f;
#pragma unroll
        for (int e = 0; e < 8; ++e) sh = fmaf(es_r[e], gss[bl * 40 + 32 + e], sh);
#pragma unroll
        for (int p = 0; p < 4; ++p) {
            const float4 v0 = *reinterpret_cast<const float4*>(&eb0[(p * U_ + u) * 8]);
            const float4 v1 = *reinterpret_cast<const float4*>(&eb0[(p * U_ + u) * 8 + 4]);
            const float bp_[8] = {v0.x, v0.y, v0.z, v0.w, v1.x, v1.y, v1.z, v1.w};
            float ta = 0.f;
#pragma unroll
            for (int e = 0; e < 8; ++e) {
                const float et = fmaxf(acc[bi][p][e] + bp_[e], 0.f);
                ta = fmaf(et, g0s[bl * 64 + p * 16 + e], ta);
                ta = fmaf(es_r[e], g0s[bl * 64 + p * 16 + 8 + e], ta);
                sh = fmaf(et, gss[bl * 40 + p * 8 + e], sh);
            }
            tout[(p * B_ + b) * U_ + u] = ta;
        }
        tout[(4 * B_ + b) * U_ + u] = sh;
    }
}

// ============================================================================
// K3: level-1 gates. Per task t: logits (B,16) = task_out0[t] (B,512) @ gw1[t]
// (512,16) + gb1[t]; softmax over 16. out: g1 (T,B,16)
// ============================================================================
__global__ __launch_bounds__(256) void gates1_kernel(
    const float* __restrict__ tin, const float* __restrict__ gw1,
    const float* __restrict__ gb1, float* __restrict__ g1)
{
    __shared__ float xs[64 * 36];   // A tile [64 b][32 k]; reused for logits [64][16]
    __shared__ float wsh[32 * 16];
    const int tid = threadIdx.x;
    const int t = blockIdx.y;
    const int b0 = blockIdx.x * 64;
    const int bl = tid >> 2;    // 0..63
    const int lane = tid & 3;   // 0..3 (4 cols each)
    const float* A = tin + (size_t)t * B_ * U_;
    float acc[4] = {0.f, 0.f, 0.f, 0.f};

    for (int k0 = 0; k0 < U_; k0 += 32) {
        __syncthreads();
#pragma unroll
        for (int s = 0; s < 2; ++s) {
            const int i = tid + s * 256;
            const int r = i >> 3, f = i & 7;
            const float4 v = *reinterpret_cast<const float4*>(&A[(b0 + r) * U_ + k0 + f * 4]);
            *reinterpret_cast<float4*>(&xs[r * 36 + f * 4]) = v;
        }
        if (tid < 128) {
            const int kk = tid >> 2, f = tid & 3;
            const float4 v = *reinterpret_cast<const float4*>(&gw1[t * (U_ * 16) + (k0 + kk) * 16 + f * 4]);
            *reinterpret_cast<float4*>(&wsh[kk * 16 + f * 4]) = v;
        }
        __syncthreads();
#pragma unroll 8
        for (int kk = 0; kk < 32; ++kk) {
            const float a = xs[bl * 36 + kk];
            const float4 w = *reinterpret_cast<const float4*>(&wsh[kk * 16 + lane * 4]);
            acc[0] = fmaf(a, w.x, acc[0]);
            acc[1] = fmaf(a, w.y, acc[1]);
            acc[2] = fmaf(a, w.z, acc[2]);
            acc[3] = fmaf(a, w.w, acc[3]);
        }
    }
    __syncthreads();
#pragma unroll
    for (int c = 0; c < 4; ++c)
        xs[bl * 16 + lane * 4 + c] = acc[c] + gb1[t * 16 + lane * 4 + c];
    __syncthreads();
    if (tid < 64) {
        float m = -1e30f;
        for (int j = 0; j < 16; ++j) m = fmaxf(m, xs[tid * 16 + j]);
        float s = 0.f;
        for (int j = 0; j < 16; ++j) { const float e = expf(xs[tid * 16 + j] - m); xs[tid * 16 + j] = e; s += e; }
        const float inv = 1.f / s;
        for (int j = 0; j < 16; ++j)
            g1[((size_t)t * B_ + b0 + tid) * 16 + j] = xs[tid * 16 + j] * inv;
    }
}

// ============================================================================
// K4: fused level-1. A planes differ per p: p<4 -> task_out0[p], p=4 -> share
// (contiguous in ws so ain + p*B*U works for all 5). K=512, Kt=16.
// out: d_out (T,B,U)
// ============================================================================
__global__ __launch_bounds__(256) void fused1_kernel(
    const float* __restrict__ ain, const float* __restrict__ ew1,
    const float* __restrict__ ews1, const float* __restrict__ eb1,
    const float* __restrict__ ebs1, const float* __restrict__ g1,
    float* __restrict__ out)
{
    __shared__ float smem[6400 + 5120];    // 46 KB
    float* as_ = smem;          // [5 p][64 b][20] (16 k used)
    float* wsh = smem + 6400;   // [5 p][16 k][64 n]
    const int tid = threadIdx.x;
    const int bp = tid >> 3, ul = tid & 7;
    const int b0 = blockIdx.x * 64;
    const int n0 = blockIdx.y * 64;
    const int u  = blockIdx.y * 8 + ul;

    float acc[2][5][8];
#pragma unroll
    for (int i = 0; i < 2; ++i)
#pragma unroll
        for (int p = 0; p < 5; ++p)
#pragma unroll
            for (int e = 0; e < 8; ++e) acc[i][p][e] = 0.f;

    for (int k0 = 0; k0 < U_; k0 += 16) {
        __syncthreads();
#pragma unroll
        for (int s = 0; s < 5; ++s) {       // A tiles: 5x64x16 = 1280 float4
            const int i = tid + s * 256;
            const int p = i >> 8;
            const int rem = i & 255;
            const int r = rem >> 2, f = rem & 3;
            const float4 v = *reinterpret_cast<const float4*>(&ain[((size_t)p * B_ + b0 + r) * U_ + k0 + f * 4]);
            *reinterpret_cast<float4*>(&as_[p * 1280 + r * 20 + f * 4]) = v;
        }
#pragma unroll
        for (int s = 0; s < 5; ++s) {       // W tiles: 5x16x64 = 1280 float4
            const int i = tid + s * 256;
            const int p = i >> 8;
            const int rem = i & 255;
            const int kk = rem >> 4, f = rem & 15;
            const float* Wp = (p < 4) ? (ew1 + p * (U_ * 4096)) : ews1;
            const float4 v = *reinterpret_cast<const float4*>(&Wp[(k0 + kk) * 4096 + n0 + f * 4]);
            *reinterpret_cast<float4*>(&wsh[p * 1024 + kk * 64 + f * 4]) = v;
        }
        __syncthreads();
#pragma unroll 2
        for (int kk = 0; kk < 16; ++kk) {
#pragma unroll
            for (int p = 0; p < 5; ++p) {
                const float a0 = as_[p * 1280 + (bp * 2 + 0) * 20 + kk];
                const float a1 = as_[p * 1280 + (bp * 2 + 1) * 20 + kk];
                const float4 w0 = *reinterpret_cast<const float4*>(&wsh[p * 1024 + kk * 64 + ul * 8]);
                const float4 w1 = *reinterpret_cast<const float4*>(&wsh[p * 1024 + kk * 64 + ul * 8 + 4]);
                const float w[8] = {w0.x, w0.y, w0.z, w0.w, w1.x, w1.y, w1.z, w1.w};
#pragma unroll
                for (int e = 0; e < 8; ++e) {
                    acc[0][p][e] = fmaf(a0, w[e], acc[0][p][e]);
                    acc[1][p][e] = fmaf(a1, w[e], acc[1][p][e]);
                }
            }
        }
    }
    // ---- epilogue ----
    __syncthreads();
    float* g1s = wsh;   // [64 b][64] (t*16+j)
    for (int i = tid; i < 64 * 64; i += 256) {
        const int r = i >> 6, c = i & 63;
        g1s[i] = g1[((c >> 4) * B_ + (b0 + r)) * 16 + (c & 15)];
    }
    __syncthreads();

    float bias4[8];
    {
        const float4 v0 = *reinterpret_cast<const float4*>(&ebs1[u * 8]);
        const float4 v1 = *reinterpret_cast<const float4*>(&ebs1[u * 8 + 4]);
        bias4[0] = v0.x; bias4[1] = v0.y; bias4[2] = v0.z; bias4[3] = v0.w;
        bias4[4] = v1.x; bias4[5] = v1.y; bias4[6] = v1.z; bias4[7] = v1.w;
    }
#pragma unroll
    for (int bi = 0; bi < 2; ++bi) {
        const int bl = bp * 2 + bi;
        const int b = b0 + bl;
        float es_r[8];
#pragma unroll
        for (int e = 0; e < 8; ++e) es_r[e] = fmaxf(acc[bi][4][e] + bias4[e], 0.f);
#pragma unroll
        for (int p = 0; p < 4; ++p) {
            const float4 v0 = *reinterpret_cast<const float4*>(&eb1[(p * U_ + u) * 8]);
            const float4 v1 = *reinterpret_cast<const float4*>(&eb1[(p * U_ + u) * 8 + 4]);
            const float bp_[8] = {v0.x, v0.y, v0.z, v0.w, v1.x, v1.y, v1.z, v1.w};
            float ta = 0.f;
#pragma unroll
            for (int e = 0; e < 8; ++e) {
                const float et = fmaxf(acc[bi][p][e] + bp_[e], 0.f);
                ta = fmaf(et, g1s[bl * 64 + p * 16 + e], ta);
                ta = fmaf(es_r[e], g1s[bl * 64 + p * 16 + 8 + e], ta);
            }
            out[((size_t)p * B_ + b) * U_ + u] = ta;
        }
    }
}

extern "C" void kernel_launch(void* const* d_in, const int* in_sizes, int n_in,
                              void* d_out, int out_size, void* d_ws, size_t ws_size,
                              hipStream_t stream) {
    const float* x    = (const float*)d_in[0];
    const float* ews0 = (const float*)d_in[1];
    const float* ebs0 = (const float*)d_in[2];
    const float* ews1 = (const float*)d_in[3];
    const float* ebs1 = (const float*)d_in[4];
    const float* gws  = (const float*)d_in[5];
    const float* gbs  = (const float*)d_in[6];
    const float* ew0  = (const float*)d_in[7];
    const float* eb0  = (const float*)d_in[8];
    const float* gw0  = (const float*)d_in[9];
    const float* gb0  = (const float*)d_in[10];
    const float* ew1  = (const float*)d_in[11];
    const float* eb1  = (const float*)d_in[12];
    const float* gw1  = (const float*)d_in[13];
    const float* gb1  = (const float*)d_in[14];

    float* ws = (float*)d_ws;
    float* g0    = ws;                                  // T*B*16   = 524288
    float* gs    = g0 + (size_t)T_ * B_ * 16;           // B*40     = 327680
    float* g1    = gs + (size_t)B_ * 40;                // T*B*16   = 524288
    float* tout0 = g1 + (size_t)T_ * B_ * 16;           // 5*B*U    = 20971520
    // total ws use: 22347776 floats = 89.4 MB

    gates0_kernel<<<dim3(B_ / 32), 256, 0, stream>>>(x, gw0, gb0, gws, gbs, g0, gs);
    fused0_kernel<<<dim3(B_ / 64, U_ / 8), 256, 0, stream>>>(x, ew0, ews0, eb0, ebs0, g0, gs, tout0);
    gates1_kernel<<<dim3(B_ / 64, T_), 256, 0, stream>>>(tout0, gw1, gb1, g1);
    fused1_kernel<<<dim3(B_ / 64, U_ / 8), 256, 0, stream>>>(tout0, ew1, ews1, eb1, ebs1, g1, (float*)d_out);
}

// Round 4
// 3566.201 us; speedup vs baseline: 2.1188x; 2.1188x over previous
//
#include <hip/hip_runtime.h>
#include <math.h>

#define T_ 4
#define B_ 8192
#define D_ 1024
#define U_ 512
#define E_ 8

typedef __attribute__((ext_vector_type(8))) short short8;
typedef __attribute__((ext_vector_type(4))) float f32x4;

// ---------- bf16 helpers (RTN-even, matches HW cvt) ----------
__device__ __forceinline__ unsigned short f2bf(float f) {
    unsigned int u = __float_as_uint(f);
    unsigned int r = (u + 0x7FFFu + ((u >> 16) & 1u)) >> 16;
    return (unsigned short)r;
}
__device__ __forceinline__ float bf2f(unsigned short h) {
    return __uint_as_float(((unsigned int)h) << 16);
}
__device__ __forceinline__ void unpack8(const uint4 v, float* y) {
    y[0] = __uint_as_float(v.x << 16); y[1] = __uint_as_float(v.x & 0xFFFF0000u);
    y[2] = __uint_as_float(v.y << 16); y[3] = __uint_as_float(v.y & 0xFFFF0000u);
    y[4] = __uint_as_float(v.z << 16); y[5] = __uint_as_float(v.z & 0xFFFF0000u);
    y[6] = __uint_as_float(v.w << 16); y[7] = __uint_as_float(v.w & 0xFFFF0000u);
}

__device__ __forceinline__ void gload16(const void* g, void* l) {
    __builtin_amdgcn_global_load_lds(
        (const __attribute__((address_space(1))) void*)g,
        (__attribute__((address_space(3))) void*)l, 16, 0, 0);
}

// ============================================================================
// xsplit: x fp32 -> xh + xl bf16 (hi/lo split)
// ============================================================================
__global__ __launch_bounds__(256) void xsplit_kernel(
    const float* __restrict__ x, unsigned short* __restrict__ xh,
    unsigned short* __restrict__ xl)
{
    const size_t i = ((size_t)blockIdx.x * 256 + threadIdx.x) * 8;
    const float4 a = *reinterpret_cast<const float4*>(&x[i]);
    const float4 b = *reinterpret_cast<const float4*>(&x[i + 4]);
    const float f[8] = {a.x, a.y, a.z, a.w, b.x, b.y, b.z, b.w};
    unsigned int hv[4], lv[4];
#pragma unroll
    for (int q = 0; q < 4; ++q) {
        const unsigned short h0 = f2bf(f[2*q]),   h1 = f2bf(f[2*q+1]);
        const unsigned short l0 = f2bf(f[2*q]   - bf2f(h0));
        const unsigned short l1 = f2bf(f[2*q+1] - bf2f(h1));
        hv[q] = (unsigned int)h0 | ((unsigned int)h1 << 16);
        lv[q] = (unsigned int)l0 | ((unsigned int)l1 << 16);
    }
    *reinterpret_cast<uint4*>(&xh[i]) = make_uint4(hv[0], hv[1], hv[2], hv[3]);
    *reinterpret_cast<uint4*>(&xl[i]) = make_uint4(lv[0], lv[1], lv[2], lv[3]);
}

// ============================================================================
// wsplit: W (K,4096) fp32 (plane p<4 from task array, p=4 share) ->
//         transposed Wt (5,4096,K) bf16 hi/lo
// ============================================================================
__global__ __launch_bounds__(256) void wsplit_kernel(
    const float* __restrict__ Wtask, const float* __restrict__ Wshare, int K,
    unsigned short* __restrict__ Wh, unsigned short* __restrict__ Wl)
{
    __shared__ float t[32][33];
    const int tid = threadIdx.x;
    const int p = blockIdx.z;
    const int n0 = blockIdx.x * 32, k0 = blockIdx.y * 32;
    const float* S = (p < 4) ? (Wtask + (size_t)p * K * 4096) : Wshare;
    {
        const int r = tid >> 3, c = (tid & 7) * 4;
        const float4 v = *reinterpret_cast<const float4*>(&S[(size_t)(k0 + r) * 4096 + n0 + c]);
        t[r][c] = v.x; t[r][c+1] = v.y; t[r][c+2] = v.z; t[r][c+3] = v.w;
    }
    __syncthreads();
    {
        const int rn = tid >> 3, kc = (tid & 7) * 4;
        unsigned short h4[4], l4[4];
#pragma unroll
        for (int q = 0; q < 4; ++q) {
            const float f = t[kc + q][rn];
            const unsigned short h = f2bf(f);
            h4[q] = h;
            l4[q] = f2bf(f - bf2f(h));
        }
        const size_t o = (size_t)p * 4096 * K + (size_t)(n0 + rn) * K + k0 + kc;
        *reinterpret_cast<ushort4*>(&Wh[o]) = make_ushort4(h4[0], h4[1], h4[2], h4[3]);
        *reinterpret_cast<ushort4*>(&Wl[o]) = make_ushort4(l4[0], l4[1], l4[2], l4[3]);
    }
}

// ============================================================================
// gates0 (fp32): g0 (T,B,16), gs (B,40)
// ============================================================================
__global__ __launch_bounds__(256) void gates0_kernel(
    const float* __restrict__ x, const float* __restrict__ gw0,
    const float* __restrict__ gb0, const float* __restrict__ gws,
    const float* __restrict__ gbs, float* __restrict__ g0,
    float* __restrict__ gs)
{
    __shared__ float xs[32 * 36];
    __shared__ float wsh[32 * 104];
    const int tid = threadIdx.x;
    const int bl = tid >> 3;
    const int lane = tid & 7;
    const int b0 = blockIdx.x * 32;

    float acc[13];
#pragma unroll
    for (int i = 0; i < 13; ++i) acc[i] = 0.f;

    for (int k0 = 0; k0 < D_; k0 += 32) {
        __syncthreads();
        {
            const int r = tid >> 3, f = tid & 7;
            const float4 v = *reinterpret_cast<const float4*>(&x[(b0 + r) * D_ + k0 + f * 4]);
            *reinterpret_cast<float4*>(&xs[r * 36 + f * 4]) = v;
        }
        for (int i = tid; i < 32 * 104; i += 256) {
            const int kk = i / 104, c = i - kk * 104;
            float v;
            if (c < 64) v = gw0[(c >> 4) * (D_ * 16) + (k0 + kk) * 16 + (c & 15)];
            else        v = gws[(k0 + kk) * 40 + (c - 64)];
            wsh[kk * 104 + c] = v;
        }
        __syncthreads();
#pragma unroll 8
        for (int kk = 0; kk < 32; ++kk) {
            const float a = xs[bl * 36 + kk];
#pragma unroll
            for (int c = 0; c < 13; ++c)
                acc[c] = fmaf(a, wsh[kk * 104 + lane * 13 + c], acc[c]);
        }
    }
    __syncthreads();
#pragma unroll
    for (int c = 0; c < 13; ++c) {
        const int col = lane * 13 + c;
        const float bias = (col < 64) ? gb0[col] : gbs[col - 64];
        wsh[bl * 104 + col] = acc[c] + bias;
    }
    __syncthreads();
    if (tid < 160) {
        const int r = tid / 5, grp = tid - (tid / 5) * 5;
        const int base = r * 104 + (grp < 4 ? grp * 16 : 64);
        const int n = (grp < 4) ? 16 : 40;
        float m = -1e30f;
        for (int j = 0; j < n; ++j) m = fmaxf(m, wsh[base + j]);
        float s = 0.f;
        for (int j = 0; j < n; ++j) { const float e = expf(wsh[base + j] - m); wsh[base + j] = e; s += e; }
        const float inv = 1.f / s;
        const int b = b0 + r;
        if (grp < 4) { for (int j = 0; j < 16; ++j) g0[(grp * B_ + b) * 16 + j] = wsh[base + j] * inv; }
        else         { for (int j = 0; j < 40; ++j) gs[b * 40 + j] = wsh[base + j] * inv; }
    }
}

// ============================================================================
// gemm3p: 3-pass split-bf16 MFMA GEMM, 128x128 tile, relu(.+bias) epilogue.
// A (rows,K) hi/lo bf16 K-major; Wt (5,4096,K) hi/lo bf16 K-major.
// Y (5,Bc,4096) bf16 = relu(A @ Wt^T + bias)
// ============================================================================
__global__ __launch_bounds__(256) void gemm3p_kernel(
    const unsigned short* __restrict__ Ah, const unsigned short* __restrict__ Al,
    long planeStrideA,
    const unsigned short* __restrict__ Wh, const unsigned short* __restrict__ Wl,
    const float* __restrict__ btask, const float* __restrict__ bshare,
    unsigned short* __restrict__ Y, int K, int Bc)
{
    __shared__ char smem[32768];   // Ah[8K] Al[8K] Bh[8K] Bl[8K], 128x32 bf16 each
    const int tid = threadIdx.x;
    const int w = tid >> 6, l = tid & 63;
    const int p = blockIdx.z;
    const int m0 = blockIdx.x * 128;
    const int n0 = blockIdx.y * 128;

    const unsigned short* Ahp = Ah + (size_t)p * planeStrideA;
    const unsigned short* Alp = Al + (size_t)p * planeStrideA;
    const unsigned short* Whp = Wh + (size_t)p * 4096 * K;
    const unsigned short* Wlp = Wl + (size_t)p * 4096 * K;

    // ---- staging: wave w stages rows [j*64 + w*16, +16) of each 128x32 tile.
    // global_load_lds writes lane l at wave_base + l*16 (linear); source col is
    // pre-swizzled (g) so the XOR-swizzled fragment read below finds its data.
    const int lr = l >> 2;                       // row within 16-row group
    const int g  = (l & 3) ^ ((l >> 3) & 3);     // pre-swizzled source k-chunk
    const unsigned short* sA[2][2];              // [hi/lo][j]
    const unsigned short* sB[2][2];
    int ldsA[2][2], ldsB[2][2];
#pragma unroll
    for (int j = 0; j < 2; ++j) {
        const int mr = j * 64 + w * 16 + lr;
        sA[0][j] = Ahp + (size_t)(m0 + mr) * K + g * 8;
        sA[1][j] = Alp + (size_t)(m0 + mr) * K + g * 8;
        sB[0][j] = Whp + (size_t)(n0 + mr) * K + g * 8;
        sB[1][j] = Wlp + (size_t)(n0 + mr) * K + g * 8;
        const int lofs = j * 4096 + w * 1024;
        ldsA[0][j] = lofs;          ldsA[1][j] = 8192 + lofs;
        ldsB[0][j] = 16384 + lofs;  ldsB[1][j] = 24576 + lofs;
    }

    // ---- fragment read offsets (loop-invariant, XOR-swizzled: 2-way max)
    const int wm = w >> 1, wn = w & 1;
    const int lm = l & 15, lq = l >> 4;
    int aoff[4], boff[4];
#pragma unroll
    for (int i = 0; i < 4; ++i) {
        const int m = wm * 64 + i * 16 + lm;
        aoff[i] = m * 64 + ((lq ^ ((m >> 1) & 3)) << 4);
        const int n = wn * 64 + i * 16 + lm;
        boff[i] = n * 64 + ((lq ^ ((n >> 1) & 3)) << 4);
    }

    f32x4 acc[4][4];
#pragma unroll
    for (int i = 0; i < 4; ++i)
#pragma unroll
        for (int j = 0; j < 4; ++j) acc[i][j] = (f32x4)0.f;

    const int nsteps = K >> 5;
    for (int s = 0; s < nsteps; ++s) {
#pragma unroll
        for (int j = 0; j < 2; ++j) {
            gload16(sA[0][j], smem + ldsA[0][j]);
            gload16(sA[1][j], smem + ldsA[1][j]);
            gload16(sB[0][j], smem + ldsB[0][j]);
            gload16(sB[1][j], smem + ldsB[1][j]);
            sA[0][j] += 32; sA[1][j] += 32; sB[0][j] += 32; sB[1][j] += 32;
        }
        __syncthreads();   // compiler drains vmcnt before s_barrier
        short8 fah[4], fal[4], fbh[4], fbl[4];
#pragma unroll
        for (int i = 0; i < 4; ++i) {
            fah[i] = *reinterpret_cast<const short8*>(smem + aoff[i]);
            fal[i] = *reinterpret_cast<const short8*>(smem + 8192 + aoff[i]);
            fbh[i] = *reinterpret_cast<const short8*>(smem + 16384 + boff[i]);
            fbl[i] = *reinterpret_cast<const short8*>(smem + 24576 + boff[i]);
        }
#pragma unroll
        for (int i = 0; i < 4; ++i)
#pragma unroll
            for (int j = 0; j < 4; ++j) {
                acc[i][j] = __builtin_amdgcn_mfma_f32_16x16x32_bf16(fah[i], fbh[j], acc[i][j], 0, 0, 0);
                acc[i][j] = __builtin_amdgcn_mfma_f32_16x16x32_bf16(fah[i], fbl[j], acc[i][j], 0, 0, 0);
                acc[i][j] = __builtin_amdgcn_mfma_f32_16x16x32_bf16(fal[i], fbh[j], acc[i][j], 0, 0, 0);
            }
        __syncthreads();   // done reading before next overwrite
    }

    // ---- epilogue: relu(acc + bias[col]) -> bf16 Y
    const float* bias = (p < 4) ? (btask + p * 4096) : bshare;
    unsigned short* Yp = Y + (size_t)p * Bc * 4096;
    float bv[4];
#pragma unroll
    for (int j = 0; j < 4; ++j) bv[j] = bias[n0 + wn * 64 + j * 16 + lm];
#pragma unroll
    for (int i = 0; i < 4; ++i) {
        const int row = m0 + wm * 64 + i * 16 + lq * 4;
#pragma unroll
        for (int j = 0; j < 4; ++j) {
            const int col = n0 + wn * 64 + j * 16 + lm;
#pragma unroll
            for (int r = 0; r < 4; ++r) {
                float v = acc[i][j][r] + bv[j];
                v = fmaxf(v, 0.f);
                Yp[(size_t)(row + r) * 4096 + col] = f2bf(v);
            }
        }
    }
}

// ============================================================================
// combine0: Y (5,Bc,4096) + gates -> tout0 hi/lo bf16 (5,B,512)
// ============================================================================
__global__ __launch_bounds__(256) void combine0_kernel(
    const unsigned short* __restrict__ Y, const float* __restrict__ g0,
    const float* __restrict__ gs, unsigned short* __restrict__ t0h,
    unsigned short* __restrict__ t0l, int c0, int Bc)
{
    __shared__ float g0s[4][64];
    __shared__ float gss[4][40];
    const int tid = threadIdx.x;
    const int ul = tid & 63, bl = tid >> 6;
    const int u = blockIdx.x * 64 + ul;
    const int bLoc = blockIdx.y * 4 + bl;
    const int bG = c0 + bLoc;
    {
        const int r = tid >> 6, c = tid & 63;
        g0s[r][c] = g0[((size_t)(c >> 4) * B_ + (c0 + blockIdx.y * 4 + r)) * 16 + (c & 15)];
        if (tid < 160) {
            const int r2 = tid / 40, c2 = tid - r2 * 40;
            gss[r2][c2] = gs[(size_t)(c0 + blockIdx.y * 4 + r2) * 40 + c2];
        }
    }
    __syncthreads();
    float y[5][8];
#pragma unroll
    for (int p = 0; p < 5; ++p) {
        const uint4 v = *reinterpret_cast<const uint4*>(&Y[((size_t)p * Bc + bLoc) * 4096 + u * 8]);
        unpack8(v, y[p]);
    }
    float sh = 0.f;
#pragma unroll
    for (int e = 0; e < 8; ++e) sh = fmaf(y[4][e], gss[bl][32 + e], sh);
#pragma unroll
    for (int p = 0; p < 4; ++p) {
        float ta = 0.f;
#pragma unroll
        for (int e = 0; e < 8; ++e) {
            ta = fmaf(y[p][e], g0s[bl][p * 16 + e], ta);
            ta = fmaf(y[4][e], g0s[bl][p * 16 + 8 + e], ta);
            sh = fmaf(y[p][e], gss[bl][p * 8 + e], sh);
        }
        const unsigned short th = f2bf(ta);
        t0h[((size_t)p * B_ + bG) * U_ + u] = th;
        t0l[((size_t)p * B_ + bG) * U_ + u] = f2bf(ta - bf2f(th));
    }
    const unsigned short shh = f2bf(sh);
    t0h[((size_t)4 * B_ + bG) * U_ + u] = shh;
    t0l[((size_t)4 * B_ + bG) * U_ + u] = f2bf(sh - bf2f(shh));
}

// ============================================================================
// gates1: logits = tout0h[t] (B,512 bf16) @ gw1[t] (512,16 fp32); softmax
// ============================================================================
__global__ __launch_bounds__(256) void gates1_kernel(
    const unsigned short* __restrict__ tin, const float* __restrict__ gw1,
    const float* __restrict__ gb1, float* __restrict__ g1)
{
    __shared__ float xs[64 * 36];
    __shared__ float wsh[32 * 16];
    const int tid = threadIdx.x;
    const int t = blockIdx.y;
    const int b0 = blockIdx.x * 64;
    const int bl = tid >> 2;
    const int lane = tid & 3;
    const unsigned short* A = tin + (size_t)t * B_ * U_;
    float acc[4] = {0.f, 0.f, 0.f, 0.f};

    for (int k0 = 0; k0 < U_; k0 += 32) {
        __syncthreads();
        {
            const int r = tid >> 2, f = tid & 3;
            const uint4 v = *reinterpret_cast<const uint4*>(&A[(size_t)(b0 + r) * U_ + k0 + f * 8]);
            unpack8(v, &xs[r * 36 + f * 8]);
        }
        if (tid < 128) {
            const int kk = tid >> 2, f = tid & 3;
            const float4 v = *reinterpret_cast<const float4*>(&gw1[(size_t)t * (U_ * 16) + (k0 + kk) * 16 + f * 4]);
            *reinterpret_cast<float4*>(&wsh[kk * 16 + f * 4]) = v;
        }
        __syncthreads();
#pragma unroll 8
        for (int kk = 0; kk < 32; ++kk) {
            const float a = xs[bl * 36 + kk];
            const float4 wv = *reinterpret_cast<const float4*>(&wsh[kk * 16 + lane * 4]);
            acc[0] = fmaf(a, wv.x, acc[0]);
            acc[1] = fmaf(a, wv.y, acc[1]);
            acc[2] = fmaf(a, wv.z, acc[2]);
            acc[3] = fmaf(a, wv.w, acc[3]);
        }
    }
    __syncthreads();
#pragma unroll
    for (int c = 0; c < 4; ++c)
        xs[bl * 16 + lane * 4 + c] = acc[c] + gb1[t * 16 + lane * 4 + c];
    __syncthreads();
    if (tid < 64) {
        float m = -1e30f;
        for (int j = 0; j < 16; ++j) m = fmaxf(m, xs[tid * 16 + j]);
        float s = 0.f;
        for (int j = 0; j < 16; ++j) { const float e = expf(xs[tid * 16 + j] - m); xs[tid * 16 + j] = e; s += e; }
        const float inv = 1.f / s;
        for (int j = 0; j < 16; ++j)
            g1[((size_t)t * B_ + b0 + tid) * 16 + j] = xs[tid * 16 + j] * inv;
    }
}

// ============================================================================
// combine1: Y (5,Bc,4096) + g1 -> out (T,B,512) fp32
// ============================================================================
__global__ __launch_bounds__(256) void combine1_kernel(
    const unsigned short* __restrict__ Y, const float* __restrict__ g1,
    float* __restrict__ out, int c0, int Bc)
{
    __shared__ float g1s[4][64];
    const int tid = threadIdx.x;
    const int ul = tid & 63, bl = tid >> 6;
    const int u = blockIdx.x * 64 + ul;
    const int bLoc = blockIdx.y * 4 + bl;
    const int bG = c0 + bLoc;
    {
        const int r = tid >> 6, c = tid & 63;
        g1s[r][c] = g1[((size_t)(c >> 4) * B_ + (c0 + blockIdx.y * 4 + r)) * 16 + (c & 15)];
    }
    __syncthreads();
    float y[5][8];
#pragma unroll
    for (int p = 0; p < 5; ++p) {
        const uint4 v = *reinterpret_cast<const uint4*>(&Y[((size_t)p * Bc + bLoc) * 4096 + u * 8]);
        unpack8(v, y[p]);
    }
#pragma unroll
    for (int p = 0; p < 4; ++p) {
        float ta = 0.f;
#pragma unroll
        for (int e = 0; e < 8; ++e) {
            ta = fmaf(y[p][e], g1s[bl][p * 16 + e], ta);
            ta = fmaf(y[4][e], g1s[bl][p * 16 + 8 + e], ta);
        }
        out[((size_t)p * B_ + bG) * U_ + u] = ta;
    }
}

// ============================================================================
extern "C" void kernel_launch(void* const* d_in, const int* in_sizes, int n_in,
                              void* d_out, int out_size, void* d_ws, size_t ws_size,
                              hipStream_t stream) {
    const float* x    = (const float*)d_in[0];
    const float* ews0 = (const float*)d_in[1];
    const float* ebs0 = (const float*)d_in[2];
    const float* ews1 = (const float*)d_in[3];
    const float* ebs1 = (const float*)d_in[4];
    const float* gws  = (const float*)d_in[5];
    const float* gbs  = (const float*)d_in[6];
    const float* ew0  = (const float*)d_in[7];
    const float* eb0  = (const float*)d_in[8];
    const float* gw0  = (const float*)d_in[9];
    const float* gb0  = (const float*)d_in[10];
    const float* ew1  = (const float*)d_in[11];
    const float* eb1  = (const float*)d_in[12];
    const float* gw1  = (const float*)d_in[13];
    const float* gb1  = (const float*)d_in[14];

    char* wsb = (char*)d_ws;
    size_t ofs = 0;
    auto alloc = [&](size_t bytes) -> char* {
        char* r = wsb + ofs;
        ofs = (ofs + bytes + 255) & ~(size_t)255;
        return r;
    };
    float* g0  = (float*)alloc(4ull * T_ * B_ * 16);
    float* gs  = (float*)alloc(4ull * B_ * 40);
    float* g1  = (float*)alloc(4ull * T_ * B_ * 16);
    unsigned short* xh  = (unsigned short*)alloc(2ull * B_ * D_);
    unsigned short* xl  = (unsigned short*)alloc(2ull * B_ * D_);
    unsigned short* w0h = (unsigned short*)alloc(2ull * 5 * 4096 * 1024);
    unsigned short* w0l = (unsigned short*)alloc(2ull * 5 * 4096 * 1024);
    unsigned short* w1h = (unsigned short*)alloc(2ull * 5 * 4096 * 512);
    unsigned short* w1l = (unsigned short*)alloc(2ull * 5 * 4096 * 512);
    unsigned short* t0h = (unsigned short*)alloc(2ull * 5 * B_ * U_);
    unsigned short* t0l = (unsigned short*)alloc(2ull * 5 * B_ * U_);
    const size_t persist = ofs;

    int Bc = B_;
    while (Bc > 128 && persist + (size_t)Bc * 5 * 4096 * 2 > ws_size) Bc >>= 1;
    unsigned short* Ybuf = (unsigned short*)alloc((size_t)Bc * 5 * 4096 * 2);

    xsplit_kernel<<<dim3(B_ * D_ / 2048), 256, 0, stream>>>(x, xh, xl);
    wsplit_kernel<<<dim3(128, 32, 5), 256, 0, stream>>>(ew0, ews0, 1024, w0h, w0l);
    wsplit_kernel<<<dim3(128, 16, 5), 256, 0, stream>>>(ew1, ews1, 512, w1h, w1l);
    gates0_kernel<<<dim3(B_ / 32), 256, 0, stream>>>(x, gw0, gb0, gws, gbs, g0, gs);

    for (int c0 = 0; c0 < B_; c0 += Bc) {
        gemm3p_kernel<<<dim3(Bc / 128, 32, 5), 256, 0, stream>>>(
            xh + (size_t)c0 * D_, xl + (size_t)c0 * D_, 0L,
            w0h, w0l, eb0, ebs0, Ybuf, 1024, Bc);
        combine0_kernel<<<dim3(8, Bc / 4), 256, 0, stream>>>(Ybuf, g0, gs, t0h, t0l, c0, Bc);
    }

    gates1_kernel<<<dim3(B_ / 64, T_), 256, 0, stream>>>(t0h, gw1, gb1, g1);

    for (int c0 = 0; c0 < B_; c0 += Bc) {
        gemm3p_kernel<<<dim3(Bc / 128, 32, 5), 256, 0, stream>>>(
            t0h + (size_t)c0 * U_, t0l + (size_t)c0 * U_, (long)B_ * U_,
            w1h, w1l, eb1, ebs1, Ybuf, 512, Bc);
        combine1_kernel<<<dim3(8, Bc / 4), 256, 0, stream>>>(Ybuf, g1, (float*)d_out, c0, Bc);
    }
}